// Round 9
// baseline (175.320 us; speedup 1.0000x reference)
//
#include <hip/hip_runtime.h>
#include <stdint.h>

#define NROWS 8192
#define MCOLS 8192
#define DDIM  64

typedef _Float16 half8   __attribute__((ext_vector_type(8)));
typedef _Float16 half4   __attribute__((ext_vector_type(4)));
typedef float    float8  __attribute__((ext_vector_type(8)));
typedef float    floatx4 __attribute__((ext_vector_type(4)));

// ---------- monotone float <-> uint key (for atomicMax argmax) ----------
__device__ __forceinline__ unsigned f2key(float f) {
  unsigned u = __float_as_uint(f);
  return (u & 0x80000000u) ? ~u : (u | 0x80000000u);
}
__device__ __forceinline__ float key2f(unsigned k) {
  unsigned u = (k & 0x80000000u) ? (k & 0x7fffffffu) : ~k;
  return __uint_as_float(u);
}

// ---------- convert y only: fp16 hi/lo split in fragment order + norms -------
// 16 threads per row, float4 loads (fully coalesced), 8-byte fragment stores.
// Fragment pos for (row,k): (row>>4)*1024 + (k>>5)*512 +
//                           (((k>>3)&3)*16 + (row&15))*8 + (k&7)
// Also zeroes the global accumulators (ws is poisoned 0xAA every call).
__global__ void convert_y_kernel(const float* __restrict__ y,
                                 _Float16* __restrict__ yh, _Float16* __restrict__ yl,
                                 float* __restrict__ yn,
                                 unsigned long long* __restrict__ rk,
                                 unsigned long long* __restrict__ ck,
                                 float* __restrict__ rs, float* __restrict__ cs) {
  const int gid = blockIdx.x * 256 + threadIdx.x;    // 0 .. 131071
  if (gid < NROWS) { rk[gid] = 0ull; rs[gid] = 0.0f; ck[gid] = 0ull; cs[gid] = 0.0f; }

  const int row = gid >> 4;                          // 0 .. 8191
  const int tq  = gid & 15;                          // quarter-of-row id
  const int k0  = tq * 4;
  float4 v = *(const float4*)(y + (size_t)row * DDIM + k0);

  half4 hb, lb;
  float s = 0.0f;
  {
    float f0 = v.x, f1 = v.y, f2 = v.z, f3 = v.w;
    _Float16 h0 = (_Float16)f0, h1 = (_Float16)f1, h2 = (_Float16)f2, h3 = (_Float16)f3;
    hb[0] = h0; hb[1] = h1; hb[2] = h2; hb[3] = h3;
    lb[0] = (_Float16)((f0 - (float)h0) * 2048.0f);
    lb[1] = (_Float16)((f1 - (float)h1) * 2048.0f);
    lb[2] = (_Float16)((f2 - (float)h2) * 2048.0f);
    lb[3] = (_Float16)((f3 - (float)h3) * 2048.0f);
    s = fmaf(f0, f0, fmaf(f1, f1, fmaf(f2, f2, f3 * f3)));
  }
  const int pos = ((row >> 4) << 10) + ((k0 >> 5) << 9)
                + ((((k0 >> 3) & 3) << 4) + (row & 15)) * 8 + (k0 & 7);
  *(half4*)(yh + pos) = hb;
  *(half4*)(yl + pos) = lb;

  // row norm: reduce over the 16 lanes of this row (lane groups are aligned)
  s += __shfl_down(s, 8);
  s += __shfl_down(s, 4);
  s += __shfl_down(s, 2);
  s += __shfl_down(s, 1);
  if (tq == 0) yn[row] = s;
}

// ---------- main pass: block = 4 waves, each wave 16 rows x 256 cols ----------
// A (x) loaded fp32 and hi/lo-split in-register ONCE per block; B (y) loaded
// pre-packed fp16. 1 panel/wave keeps VGPR <= 64 for 8 waves/SIMD residency.
__global__ __launch_bounds__(256, 8) void mfma_tile_kernel(
    const float* __restrict__ x,
    const _Float16* __restrict__ yh, const _Float16* __restrict__ yl,
    const float* __restrict__ yn,
    unsigned long long* __restrict__ row_key, float* __restrict__ row_sum,
    unsigned long long* __restrict__ col_key, float* __restrict__ col_sum)
{
  __shared__ unsigned long long lkey[256];   // per-block col keys (2 KB)
  __shared__ float              lsum[256];   //                    (1 KB)

  const int wave = threadIdx.x >> 6;
  const int lane = threadIdx.x & 63;
  const int l15  = lane & 15;
  const int grp  = lane >> 4;                // k-group (A/B) == row-group (C/D)
  const int ap   = blockIdx.y * 4 + wave;    // A panel (16 rows)
  const int ro   = ap * 16 + grp * 4;        // first C/D row this lane covers
  const int colbase = blockIdx.x * 256;

  lkey[threadIdx.x] = 0ull;
  lsum[threadIdx.x] = 0.0f;
  __syncthreads();

  // ---- A fragments: load fp32, split hi/lo, compute panel norms ----
  half8 Ah0, Ah1, Al0, Al1;
  float normA;
  {
    const float* ax = x + (size_t)(ap * 16 + l15) * DDIM + grp * 8;
    float8 f0 = *(const float8*)ax;          // k = grp*8 + j
    float8 f1 = *(const float8*)(ax + 32);   // k = 32 + grp*8 + j
    float pa = 0.0f;
    #pragma unroll
    for (int j = 0; j < 8; ++j) {
      _Float16 h0 = (_Float16)f0[j];
      _Float16 h1 = (_Float16)f1[j];
      Ah0[j] = h0;  Al0[j] = (_Float16)((f0[j] - (float)h0) * 2048.0f);
      Ah1[j] = h1;  Al1[j] = (_Float16)((f1[j] - (float)h1) * 2048.0f);
      pa = fmaf(f0[j], f0[j], pa);
      pa = fmaf(f1[j], f1[j], pa);
    }
    pa += __shfl_xor(pa, 16);
    pa += __shfl_xor(pa, 32);
    normA = pa;                              // norm of x-row ap*16 + l15
  }

  float xne[4], rsum[4], rmax[4]; int ridx[4];
  #pragma unroll
  for (int r = 0; r < 4; ++r) {
    xne[r]  = __shfl(normA, grp * 4 + r);    // norm of C/D row ro + r
    rsum[r] = 0.0f; rmax[r] = -3.4e38f; ridx[r] = 0;
  }

  const half8* yh8 = (const half8*)yh;
  const half8* yl8 = (const half8*)yl;

  // ---- jt loop over 16 col panels ----
  for (int jt = 0; jt < 16; ++jt) {
    const size_t b0 = (size_t)(blockIdx.x * 16 + jt) * 128 + lane;
    const half8 bh0 = yh8[b0], bh1 = yh8[b0 + 64];
    const half8 bl0 = yl8[b0], bl1 = yl8[b0 + 64];
    const int col = colbase + jt * 16 + l15;
    const float ync = yn[col];

    floatx4 c1 = {}, c2 = {};
    c1 = __builtin_amdgcn_mfma_f32_16x16x32_f16(Ah0, bh0, c1, 0, 0, 0);
    c1 = __builtin_amdgcn_mfma_f32_16x16x32_f16(Ah1, bh1, c1, 0, 0, 0);
    c2 = __builtin_amdgcn_mfma_f32_16x16x32_f16(Al0, bh0, c2, 0, 0, 0);
    c2 = __builtin_amdgcn_mfma_f32_16x16x32_f16(Al1, bh1, c2, 0, 0, 0);
    c2 = __builtin_amdgcn_mfma_f32_16x16x32_f16(Ah0, bl0, c2, 0, 0, 0);
    c2 = __builtin_amdgcn_mfma_f32_16x16x32_f16(Ah1, bl1, c2, 0, 0, 0);

    float csum = 0.0f, cmax = -3.4e38f; int cr = 0;
    #pragma unroll
    for (int r = 0; r < 4; ++r) {
      float dot = fmaf(c2[r], (1.0f / 2048.0f), c1[r]);
      float sq  = fmaxf(fmaf(-2.0f, dot, xne[r] + ync), 0.0f);
      float d   = 2.0f - __builtin_amdgcn_sqrtf(sq);
      float e   = __expf(d);
      rsum[r] += e;  csum += e;
      if (d > rmax[r]) ridx[r] = col;        // cols ascend over jt -> first max
      rmax[r] = fmaxf(rmax[r], d);
      if (d > cmax) cr = r;                  // rows ascend with r -> first max
      cmax = fmaxf(cmax, d);
    }

    // ---- col partial -> LDS atomics (DS pipe); ~idx tie-break = lowest row --
    unsigned long long ckey =
        ((unsigned long long)f2key(cmax) << 32) |
        (unsigned long long)(unsigned)(~(unsigned)(ro + cr));
    atomicMax(&lkey[jt * 16 + l15], ckey);
    atomicAdd(&lsum[jt * 16 + l15], csum);
  }

  // ---- row reduce: one butterfly over the 16 lane-columns ----
  unsigned long long rkk[4];
  #pragma unroll
  for (int r = 0; r < 4; ++r)
    rkk[r] = ((unsigned long long)f2key(rmax[r]) << 32) |
             (unsigned long long)(unsigned)(~(unsigned)ridx[r]);
  #pragma unroll
  for (int off = 1; off < 16; off <<= 1) {
    #pragma unroll
    for (int r = 0; r < 4; ++r) {
      rsum[r] += __shfl_xor(rsum[r], off);
      unsigned long long o = __shfl_xor(rkk[r], off);
      if (o > rkk[r]) rkk[r] = o;
    }
  }
  if (l15 == 0) {
    #pragma unroll
    for (int r = 0; r < 4; ++r) {
      atomicMax(row_key + ro + r, rkk[r]);
      atomicAdd(row_sum + ro + r, rsum[r]);
    }
  }

  // ---- block-level col flush: 1 atomic pair per col ----
  __syncthreads();
  {
    int col = colbase + threadIdx.x;
    atomicMax(col_key + col, lkey[threadIdx.x]);
    atomicAdd(col_sum + col, lsum[threadIdx.x]);
  }
}

// ---------- finalize: unpack keys, mutual test, write outputs ----------
__global__ void finalize_kernel(const unsigned long long* __restrict__ row_key,
                                const float* __restrict__ row_sum,
                                const unsigned long long* __restrict__ col_key,
                                const float* __restrict__ col_sum,
                                float* __restrict__ out)
{
  int j = blockIdx.x * 256 + threadIdx.x;
  if (j >= MCOLS) return;
  unsigned long long ck = col_key[j];
  int   ci   = (int)(~(unsigned)ck);
  float cmax = key2f((unsigned)(ck >> 32));
  float lp_col = cmax - logf(col_sum[j]);

  unsigned long long rk = row_key[ci];
  int   rj   = (int)(~(unsigned)rk);
  float rmax = key2f((unsigned)(rk >> 32));
  float lp_row = rmax - logf(row_sum[ci]);

  int mut = (rj == j);
  out[j]                 = mut ? (lp_row + lp_col) : 0.0f;
  out[MCOLS + 2 * j + 0] = (float)ci;
  out[MCOLS + 2 * j + 1] = (float)j;
  out[3 * MCOLS + j]     = mut ? 1.0f : 0.0f;
}

extern "C" void kernel_launch(void* const* d_in, const int* in_sizes, int n_in,
                              void* d_out, int out_size, void* d_ws, size_t ws_size,
                              hipStream_t stream) {
  const float* x = (const float*)d_in[0];
  const float* y = (const float*)d_in[1];
  float* out = (float*)d_out;

  char* ws = (char*)d_ws;
  unsigned long long* row_key = (unsigned long long*)(ws);            // 64 KB
  unsigned long long* col_key = (unsigned long long*)(ws + 65536);    // 64 KB
  float* row_sum = (float*)(ws + 131072);                             // 32 KB
  float* col_sum = (float*)(ws + 163840);                             // 32 KB
  float* yn      = (float*)(ws + 196608);                             // 32 KB
  _Float16* yh = (_Float16*)(ws + 229376);                            // 1 MB
  _Float16* yl = (_Float16*)(ws + 229376 + 1048576);                  // 1 MB

  convert_y_kernel<<<512, 256, 0, stream>>>(y, yh, yl, yn,
                                            row_key, col_key, row_sum, col_sum);
  dim3 grid(MCOLS / 256, NROWS / 64);      // 32 x 128 blocks, 256 threads
  mfma_tile_kernel<<<grid, 256, 0, stream>>>(x, yh, yl, yn,
                                             row_key, row_sum, col_key, col_sum);
  finalize_kernel<<<32, 256, 0, stream>>>(row_key, row_sum, col_key, col_sum, out);
}